// Round 9
// baseline (355.885 us; speedup 1.0000x reference)
//
#include <hip/hip_runtime.h>

// Multi-head attention, B=4 S=2048 D=768 H=8 DH=96. FP32 I/O, f16 MFMA compute.
// R9: (a) GEMM grids swapped to x=n-tile (fast), y=m-tile: the 12 blocks
//     sharing one 393KB A-tile run adjacently -> A read once from HBM
//     (was 12x = ~300MB/unit, the stubborn ~45us/unit across R3-R8);
//     (b) attn: 2 q-row-sets per wave (wave owns 32 rows) -> each Ks/Vt LDS
//     read feeds 2 MFMAs, halving the dominant LDS read traffic.

typedef unsigned short u16;
typedef _Float16 h16;
typedef h16 h16x8 __attribute__((ext_vector_type(8)));
typedef __fp16 fp16x2 __attribute__((ext_vector_type(2)));
typedef unsigned short u16x8 __attribute__((ext_vector_type(8)));
typedef unsigned short u16x4 __attribute__((ext_vector_type(4)));
typedef float f32x4 __attribute__((ext_vector_type(4)));

__device__ __forceinline__ u16 f2h(float f) {
  union { h16 h; u16 u; } c; c.h = (h16)f; return c.u;
}

__device__ __forceinline__ void gll16(const void* g, void* l) {
  __builtin_amdgcn_global_load_lds(
      (const __attribute__((address_space(1))) void*)g,
      (__attribute__((address_space(3))) void*)l, 16, 0, 0);
}

// ---------------------------------------------------------------------------
// prep: WqT/WkT/WvT [n=h*96+kk][d] from W[h][d][kk]; WoT [n][k] from Wo[k][n]
// ---------------------------------------------------------------------------
__global__ __launch_bounds__(256) void prep_kernel(
    const float* __restrict__ Wq, const float* __restrict__ Wk,
    const float* __restrict__ Wv, const float* __restrict__ Wo,
    u16* __restrict__ WqT, u16* __restrict__ WkT,
    u16* __restrict__ WvT, u16* __restrict__ WoT)
{
  int idx = (blockIdx.x * 256 + threadIdx.x) * 8;
  int region = idx / 589824;
  int i = idx % 589824;
  int n = i / 768;
  int d = i % 768;
  u16x8 v;
  if (region == 3) {
    #pragma unroll
    for (int j = 0; j < 8; j++) v[j] = f2h(Wo[(size_t)(d + j) * 768 + n]);
    *(u16x8*)(&WoT[i]) = v;
  } else {
    int h = n / 96, kk = n % 96;
    const float* W = (region == 0) ? Wq : (region == 1) ? Wk : Wv;
    u16* T = (region == 0) ? WqT : (region == 1) ? WkT : WvT;
    #pragma unroll
    for (int j = 0; j < 8; j++) v[j] = f2h(W[(size_t)h * 73728 + (size_t)(d + j) * 96 + kk]);
    *(u16x8*)(&T[i]) = v;
  }
}

// ---------------------------------------------------------------------------
// Batched QKV GEMM, grid (12, 64, 3): x=n-tile (fast -> A-tile L2/L3 reuse),
// y=m-tile, z selects Q/K/V. A fp32 staged with in-register cvt + prefetch.
// ---------------------------------------------------------------------------
#define GK 768

__global__ __launch_bounds__(256) void gemm_qkv(
    const float* __restrict__ Xq, const float* __restrict__ Xk,
    const float* __restrict__ Xv, const u16* __restrict__ WT,
    const float* __restrict__ bq, const float* __restrict__ bk,
    const float* __restrict__ bv,
    u16* __restrict__ Q16, u16* __restrict__ K16, u16* __restrict__ VT)
{
  const int z = blockIdx.z;
  const float* A = (z == 0) ? Xq : (z == 1) ? Xk : Xv;
  const u16* BT = WT + (size_t)z * 589824;
  const float* bias = (z == 0) ? bq : (z == 1) ? bk : bv;

  __shared__ __align__(16) u16 As[128 * 32];
  __shared__ __align__(16) u16 Bs[64 * 32];
  const int tid = threadIdx.x;
  const int wave = tid >> 6;
  const int lane = tid & 63;
  const int quad = lane >> 4;
  const int l16 = lane & 15;
  const int m0 = blockIdx.y * 128;   // swapped: y = m-tile
  const int n0 = blockIdx.x * 64;    // swapped: x = n-tile (fast)

  f32x4 acc[2][4];
  #pragma unroll
  for (int i = 0; i < 2; i++)
    #pragma unroll
    for (int j = 0; j < 4; j++) acc[i][j] = (f32x4){0.f, 0.f, 0.f, 0.f};

  const int ar = tid >> 2;
  const int ac = (tid & 3) * 8;

  f32x4 pf[4];
  u16x8 pb;
  {
    pf[0] = *(const f32x4*)(&A[(size_t)(m0 + ar) * GK + ac]);
    pf[1] = *(const f32x4*)(&A[(size_t)(m0 + ar) * GK + ac + 4]);
    pf[2] = *(const f32x4*)(&A[(size_t)(m0 + 64 + ar) * GK + ac]);
    pf[3] = *(const f32x4*)(&A[(size_t)(m0 + 64 + ar) * GK + ac + 4]);
    pb = *(const u16x8*)(&BT[(size_t)(n0 + ar) * GK + ac]);
  }

  for (int kt = 0; kt < 24; kt++) {
    u16x8 h0, h1;
    #pragma unroll
    for (int j = 0; j < 4; j++) {
      h0[j] = f2h(pf[0][j]); h0[4 + j] = f2h(pf[1][j]);
      h1[j] = f2h(pf[2][j]); h1[4 + j] = f2h(pf[3][j]);
    }
    *(u16x8*)(&As[ar * 32 + ac]) = h0;
    *(u16x8*)(&As[(64 + ar) * 32 + ac]) = h1;
    *(u16x8*)(&Bs[ar * 32 + ac]) = pb;
    __syncthreads();

    if (kt + 1 < 24) {
      const int k0 = (kt + 1) * 32;
      pf[0] = *(const f32x4*)(&A[(size_t)(m0 + ar) * GK + k0 + ac]);
      pf[1] = *(const f32x4*)(&A[(size_t)(m0 + ar) * GK + k0 + ac + 4]);
      pf[2] = *(const f32x4*)(&A[(size_t)(m0 + 64 + ar) * GK + k0 + ac]);
      pf[3] = *(const f32x4*)(&A[(size_t)(m0 + 64 + ar) * GK + k0 + ac + 4]);
      pb = *(const u16x8*)(&BT[(size_t)(n0 + ar) * GK + k0 + ac]);
    }

    h16x8 af[2], bf[4];
    #pragma unroll
    for (int mf = 0; mf < 2; mf++)
      af[mf] = *(const h16x8*)(&As[(wave * 32 + mf * 16 + l16) * 32 + quad * 8]);
    #pragma unroll
    for (int nf = 0; nf < 4; nf++)
      bf[nf] = *(const h16x8*)(&Bs[(nf * 16 + l16) * 32 + quad * 8]);
    #pragma unroll
    for (int mf = 0; mf < 2; mf++)
      #pragma unroll
      for (int nf = 0; nf < 4; nf++)
        acc[mf][nf] = __builtin_amdgcn_mfma_f32_16x16x32_f16(af[mf], bf[nf], acc[mf][nf], 0, 0, 0);

    if (kt + 1 < 24) __syncthreads();
  }

  u16* Yr = (z == 0) ? Q16 : K16;
  #pragma unroll
  for (int nf = 0; nf < 4; nf++) {
    const int n = n0 + nf * 16 + l16;
    const float bv2 = bias[n];
    #pragma unroll
    for (int mf = 0; mf < 2; mf++) {
      const int m = m0 + wave * 32 + mf * 16 + quad * 4;
      if (z == 2) {
        const int b = m >> 11, s = m & 2047;
        u16x4 pk;
        #pragma unroll
        for (int r = 0; r < 4; r++) pk[r] = f2h(acc[mf][nf][r] + bv2);
        *(u16x4*)(&VT[(size_t)b * 768 * 2048 + (size_t)n * 2048 + s]) = pk;
      } else {
        #pragma unroll
        for (int r = 0; r < 4; r++)
          Yr[(size_t)(m + r) * GK + n] = f2h(acc[mf][nf][r] + bv2);
      }
    }
  }
}

// ---------------------------------------------------------------------------
// GEMM_O, grid (12, 64): x=n-tile fast. gll16 staging (A already f16).
// ---------------------------------------------------------------------------
__global__ __launch_bounds__(256) void gemm_o(
    const u16* __restrict__ A, const u16* __restrict__ BT,
    const float* __restrict__ bias, float* __restrict__ Y)
{
  __shared__ __align__(16) u16 As[128 * 32];
  __shared__ __align__(16) u16 Bs[64 * 32];
  const int tid = threadIdx.x;
  const int wave = tid >> 6;
  const int lane = tid & 63;
  const int quad = lane >> 4;
  const int l16 = lane & 15;
  const int m0 = blockIdx.y * 128;
  const int n0 = blockIdx.x * 64;

  f32x4 acc[2][4];
  #pragma unroll
  for (int i = 0; i < 2; i++)
    #pragma unroll
    for (int j = 0; j < 4; j++) acc[i][j] = (f32x4){0.f, 0.f, 0.f, 0.f};

  const int Lr = lane >> 2, Lc = (lane & 3) * 8;
  const u16* gA0 = A + (size_t)(m0 + wave * 32 + Lr) * GK + Lc;
  const u16* gA1 = gA0 + (size_t)16 * GK;
  const u16* gB  = BT + (size_t)(n0 + wave * 16 + Lr) * GK + Lc;
  u16* lA0 = &As[(wave * 32) * 32];
  u16* lA1 = &As[(wave * 32 + 16) * 32];
  u16* lB  = &Bs[(wave * 16) * 32];

  for (int kt = 0; kt < 24; kt++) {
    gll16(gA0, lA0);
    gll16(gA1, lA1);
    gll16(gB, lB);
    gA0 += 32; gA1 += 32; gB += 32;
    __syncthreads();

    h16x8 af[2], bf[4];
    #pragma unroll
    for (int mf = 0; mf < 2; mf++)
      af[mf] = *(const h16x8*)(&As[(wave * 32 + mf * 16 + l16) * 32 + quad * 8]);
    #pragma unroll
    for (int nf = 0; nf < 4; nf++)
      bf[nf] = *(const h16x8*)(&Bs[(nf * 16 + l16) * 32 + quad * 8]);
    #pragma unroll
    for (int mf = 0; mf < 2; mf++)
      #pragma unroll
      for (int nf = 0; nf < 4; nf++)
        acc[mf][nf] = __builtin_amdgcn_mfma_f32_16x16x32_f16(af[mf], bf[nf], acc[mf][nf], 0, 0, 0);
    __syncthreads();
  }

  #pragma unroll
  for (int nf = 0; nf < 4; nf++) {
    const int n = n0 + nf * 16 + l16;
    const float bv = bias[n];
    #pragma unroll
    for (int mf = 0; mf < 2; mf++) {
      const int m = m0 + wave * 32 + mf * 16 + quad * 4;
      #pragma unroll
      for (int r = 0; r < 4; r++)
        Y[(size_t)(m + r) * GK + n] = acc[mf][nf][r] + bv;
    }
  }
}

// ---------------------------------------------------------------------------
// Flash attention, S^T formulation, V^T input, 2 q-row-sets per wave.
// Block: 256 thr (4 waves), 128 q-rows; wave owns 32 rows (sets 0/1); lane owns
// q-rows wave*32+l16 and +16. Each Ks/Vt LDS read feeds 2 MFMAs.
// ---------------------------------------------------------------------------
#define SEQ 2048
#define LQK 104
#define LVT 72
#define LPS 72

__global__ __launch_bounds__(256, 3) void attn_kernel(
    const u16* __restrict__ Q, const u16* __restrict__ K,
    const u16* __restrict__ VT, u16* __restrict__ O)
{
  __shared__ __align__(16) u16 Ks[64 * LQK];     // 13.3 KB
  __shared__ __align__(16) u16 Vt[96 * LVT];     // 13.8 KB
  __shared__ __align__(16) u16 Ps[4][32 * LPS];  // 18.4 KB

  const int tid = threadIdx.x;
  const int wave = tid >> 6;
  const int lane = tid & 63;
  const int quad = lane >> 4;
  const int l16 = lane & 15;

  const int bh = blockIdx.y;
  const int b = bh >> 3, h = bh & 7;
  const int q0 = blockIdx.x * 128;

  const size_t batch_off = (size_t)b * SEQ * 768;
  const u16* Kg = K + batch_off + h * 96;
  const u16* Vg = VT + (size_t)b * 768 * 2048 + (size_t)(h * 96) * 2048;

  h16x8 qf[2][3];
  #pragma unroll
  for (int set = 0; set < 2; set++) {
    const u16* Qrow = Q + batch_off + (size_t)(q0 + wave * 32 + set * 16 + l16) * 768 + h * 96 + quad * 8;
    #pragma unroll
    for (int ks = 0; ks < 3; ks++) qf[set][ks] = *(const h16x8*)(&Qrow[ks * 32]);
  }

  // staging: 768 K-chunks and 768 V-chunks over 256 threads (3 each)
  int krr[3], kcc[3], vrr[3], vcc[3];
  #pragma unroll
  for (int j = 0; j < 3; j++) {
    int c = tid + j * 256;
    krr[j] = c / 12;  kcc[j] = (c % 12) * 8;
    vrr[j] = c >> 3;  vcc[j] = (c & 7) * 8;
  }

  f32x4 o[2][6];
  #pragma unroll
  for (int set = 0; set < 2; set++)
    #pragma unroll
    for (int i = 0; i < 6; i++) o[set][i] = (f32x4){0.f, 0.f, 0.f, 0.f};
  float m_raw[2] = {-1e30f, -1e30f}, lrow[2] = {0.f, 0.f};
  const float sc = 0.14724498f;  // log2(e)/sqrt(96)

  u16* Pw = &Ps[wave][0];

  u16x8 kA[3], vA[3];
  #pragma unroll
  for (int j = 0; j < 3; j++) {
    kA[j] = *(const u16x8*)(&Kg[(size_t)krr[j] * 768 + kcc[j]]);
    vA[j] = *(const u16x8*)(&Vg[(size_t)vrr[j] * 2048 + vcc[j]]);
  }

  for (int kt = 0; kt < SEQ / 64; kt++) {
    #pragma unroll
    for (int j = 0; j < 3; j++) {
      *(u16x8*)(&Ks[krr[j] * LQK + kcc[j]]) = kA[j];
      *(u16x8*)(&Vt[vrr[j] * LVT + vcc[j]]) = vA[j];
    }
    __syncthreads();

    if (kt + 1 < SEQ / 64) {
      const u16* Kn = Kg + (size_t)(kt + 1) * 64 * 768;
      const u16* Vn = Vg + (size_t)(kt + 1) * 64;
      #pragma unroll
      for (int j = 0; j < 3; j++) {
        kA[j] = *(const u16x8*)(&Kn[(size_t)krr[j] * 768 + kcc[j]]);
        vA[j] = *(const u16x8*)(&Vn[(size_t)vrr[j] * 2048 + vcc[j]]);
      }
    }

    // S^T = K·Q^T, both sets share each Ks read
    f32x4 s[2][4];
    #pragma unroll
    for (int set = 0; set < 2; set++)
      #pragma unroll
      for (int kf = 0; kf < 4; kf++) s[set][kf] = (f32x4){0.f, 0.f, 0.f, 0.f};
    #pragma unroll
    for (int ks = 0; ks < 3; ks++) {
      #pragma unroll
      for (int kf = 0; kf < 4; kf++) {
        h16x8 a = *(const h16x8*)(&Ks[(kf * 16 + l16) * LQK + ks * 32 + quad * 8]);
        s[0][kf] = __builtin_amdgcn_mfma_f32_16x16x32_f16(a, qf[0][ks], s[0][kf], 0, 0, 0);
        s[1][kf] = __builtin_amdgcn_mfma_f32_16x16x32_f16(a, qf[1][ks], s[1][kf], 0, 0, 0);
      }
    }

    // online softmax per set
    #pragma unroll
    for (int set = 0; set < 2; set++) {
      float mx = s[set][0][0];
      #pragma unroll
      for (int kf = 0; kf < 4; kf++)
        #pragma unroll
        for (int r = 0; r < 4; r++) mx = fmaxf(mx, s[set][kf][r]);
      mx = fmaxf(mx, __shfl_xor(mx, 16));
      mx = fmaxf(mx, __shfl_xor(mx, 32));
      const float mold = m_raw[set];
      m_raw[set] = fmaxf(mold, mx);
      const float c0 = sc * m_raw[set];
      float ps = 0.f;
      #pragma unroll
      for (int kf = 0; kf < 4; kf++)
        #pragma unroll
        for (int r = 0; r < 4; r++) {
          float p = exp2f(fmaf(s[set][kf][r], sc, -c0));
          s[set][kf][r] = p;
          ps += p;
        }
      if (__any(m_raw[set] > mold)) {
        const float alpha = exp2f(sc * (mold - m_raw[set]));
        lrow[set] *= alpha;
        #pragma unroll
        for (int nfo = 0; nfo < 6; nfo++)
          #pragma unroll
          for (int r = 0; r < 4; r++) o[set][nfo][r] *= alpha;
      }
      lrow[set] += ps;

      #pragma unroll
      for (int kf = 0; kf < 4; kf++)
        #pragma unroll
        for (int rp = 0; rp < 4; rp += 2) {
          fp16x2 pk = __builtin_amdgcn_cvt_pkrtz(s[set][kf][rp], s[set][kf][rp + 1]);
          *(fp16x2*)(&Pw[(set * 16 + l16) * LPS + kf * 16 + quad * 4 + rp]) = pk;
        }
    }

    // O^T = V^T·P^T, both sets share each Vt read
    #pragma unroll
    for (int ks = 0; ks < 2; ks++) {
      h16x8 p0 = *(const h16x8*)(&Pw[l16 * LPS + ks * 32 + quad * 8]);
      h16x8 p1 = *(const h16x8*)(&Pw[(16 + l16) * LPS + ks * 32 + quad * 8]);
      #pragma unroll
      for (int nfo = 0; nfo < 6; nfo++) {
        h16x8 vfr = *(const h16x8*)(&Vt[(nfo * 16 + l16) * LVT + ks * 32 + quad * 8]);
        o[0][nfo] = __builtin_amdgcn_mfma_f32_16x16x32_f16(vfr, p0, o[0][nfo], 0, 0, 0);
        o[1][nfo] = __builtin_amdgcn_mfma_f32_16x16x32_f16(vfr, p1, o[1][nfo], 0, 0, 0);
      }
    }
    __syncthreads();
  }

  #pragma unroll
  for (int set = 0; set < 2; set++) {
    float l = lrow[set];
    l += __shfl_xor(l, 16);
    l += __shfl_xor(l, 32);
    const float inv = 1.0f / l;
    u16* Ob = O + batch_off + (size_t)(q0 + wave * 32 + set * 16 + l16) * 768 + h * 96;
    #pragma unroll
    for (int nfo = 0; nfo < 6; nfo++) {
      fp16x2 lo = __builtin_amdgcn_cvt_pkrtz(o[set][nfo][0] * inv, o[set][nfo][1] * inv);
      fp16x2 hi = __builtin_amdgcn_cvt_pkrtz(o[set][nfo][2] * inv, o[set][nfo][3] * inv);
      *(fp16x2*)(&Ob[nfo * 16 + quad * 4]) = lo;
      *(fp16x2*)(&Ob[nfo * 16 + quad * 4 + 2]) = hi;
    }
  }
}

// ---------------------------------------------------------------------------
extern "C" void kernel_launch(void* const* d_in, const int* in_sizes, int n_in,
                              void* d_out, int out_size, void* d_ws, size_t ws_size,
                              hipStream_t stream) {
  const float* Xq = (const float*)d_in[0];
  const float* Xk = (const float*)d_in[1];
  const float* Xv = (const float*)d_in[2];
  const float* Wq = (const float*)d_in[3];
  const float* bq = (const float*)d_in[4];
  const float* Wk = (const float*)d_in[5];
  const float* bk = (const float*)d_in[6];
  const float* Wv = (const float*)d_in[7];
  const float* bv = (const float*)d_in[8];
  const float* Wo = (const float*)d_in[9];
  const float* bo = (const float*)d_in[10];

  u16* wsu = (u16*)d_ws;
  u16* WT  = wsu;                    // WqT | WkT | WvT
  u16* WoT = wsu + 3 * 589824;
  u16* Q16 = wsu + 4 * 589824;       // 12.6 MB

  u16* outu = (u16*)d_out;
  u16* VTb = outu;                   // V^T f16 [4][768][2048]
  u16* K16 = outu + 6291456;         // K f16 rowmajor

  u16* A16 = (u16*)d_in[0];          // attn out (Xq dead after QKV GEMM)

  prep_kernel<<<1152, 256, 0, stream>>>(Wq, Wk, Wv, Wo, WT, WT + 589824, WT + 2 * 589824, WoT);
  gemm_qkv<<<dim3(12, 64, 3), 256, 0, stream>>>(Xq, Xk, Xv, WT, bq, bk, bv, Q16, K16, VTb);
  attn_kernel<<<dim3(16, 32), 256, 0, stream>>>(Q16, K16, VTb, A16);
  gemm_o<<<dim3(12, 64), 256, 0, stream>>>(A16, WoT, bo, (float*)d_out);
}

// Round 10
// 328.560 us; speedup vs baseline: 1.0832x; 1.0832x over previous
//
#include <hip/hip_runtime.h>

// Multi-head attention, B=4 S=2048 D=768 H=8 DH=96. FP32 I/O, f16 MFMA compute.
// R10: (a) GEMMs use XCD-aware swizzle: 1-D grid, c=bid&7 selects XCD
//      (round-robin dispatch), the 12 n-blocks sharing one A-tile are j/12-
//      grouped on one XCD -> A-tile served from that XCD's 4MB L2 (R9 showed
//      3-4x A over-fetch from cross-XCD scatter);
//      (b) attn: 2 q-row-sets per wave (R9's LDS halving) x 512-thread blocks
//      (R8's occupancy): LDS 64000B just under the 64KB workgroup cap,
//      grid (8,32), 8 waves/CU.

typedef unsigned short u16;
typedef _Float16 h16;
typedef h16 h16x8 __attribute__((ext_vector_type(8)));
typedef __fp16 fp16x2 __attribute__((ext_vector_type(2)));
typedef unsigned short u16x8 __attribute__((ext_vector_type(8)));
typedef unsigned short u16x4 __attribute__((ext_vector_type(4)));
typedef float f32x4 __attribute__((ext_vector_type(4)));

__device__ __forceinline__ u16 f2h(float f) {
  union { h16 h; u16 u; } c; c.h = (h16)f; return c.u;
}

__device__ __forceinline__ void gll16(const void* g, void* l) {
  __builtin_amdgcn_global_load_lds(
      (const __attribute__((address_space(1))) void*)g,
      (__attribute__((address_space(3))) void*)l, 16, 0, 0);
}

// ---------------------------------------------------------------------------
// prep: WqT/WkT/WvT [n=h*96+kk][d] from W[h][d][kk]; WoT [n][k] from Wo[k][n]
// ---------------------------------------------------------------------------
__global__ __launch_bounds__(256) void prep_kernel(
    const float* __restrict__ Wq, const float* __restrict__ Wk,
    const float* __restrict__ Wv, const float* __restrict__ Wo,
    u16* __restrict__ WqT, u16* __restrict__ WkT,
    u16* __restrict__ WvT, u16* __restrict__ WoT)
{
  int idx = (blockIdx.x * 256 + threadIdx.x) * 8;
  int region = idx / 589824;
  int i = idx % 589824;
  int n = i / 768;
  int d = i % 768;
  u16x8 v;
  if (region == 3) {
    #pragma unroll
    for (int j = 0; j < 8; j++) v[j] = f2h(Wo[(size_t)(d + j) * 768 + n]);
    *(u16x8*)(&WoT[i]) = v;
  } else {
    int h = n / 96, kk = n % 96;
    const float* W = (region == 0) ? Wq : (region == 1) ? Wk : Wv;
    u16* T = (region == 0) ? WqT : (region == 1) ? WkT : WvT;
    #pragma unroll
    for (int j = 0; j < 8; j++) v[j] = f2h(W[(size_t)h * 73728 + (size_t)(d + j) * 96 + kk]);
    *(u16x8*)(&T[i]) = v;
  }
}

// ---------------------------------------------------------------------------
// Batched QKV GEMM, 1-D grid 2304, XCD-swizzled: c=bid&7, j=bid>>3,
// yz=c*24+j/12, x=j%12 -> 12 n-blocks of each A-tile adjacent on one XCD.
// ---------------------------------------------------------------------------
#define GK 768

__global__ __launch_bounds__(256) void gemm_qkv(
    const float* __restrict__ Xq, const float* __restrict__ Xk,
    const float* __restrict__ Xv, const u16* __restrict__ WT,
    const float* __restrict__ bq, const float* __restrict__ bk,
    const float* __restrict__ bv,
    u16* __restrict__ Q16, u16* __restrict__ K16, u16* __restrict__ VT)
{
  const int bid = blockIdx.x;
  const int c = bid & 7, j = bid >> 3;
  const int yz = c * 24 + j / 12;      // 0..191
  const int xb = j % 12;
  const int yb = yz & 63, z = yz >> 6;

  const float* A = (z == 0) ? Xq : (z == 1) ? Xk : Xv;
  const u16* BT = WT + (size_t)z * 589824;
  const float* bias = (z == 0) ? bq : (z == 1) ? bk : bv;

  __shared__ __align__(16) u16 As[128 * 32];
  __shared__ __align__(16) u16 Bs[64 * 32];
  const int tid = threadIdx.x;
  const int wave = tid >> 6;
  const int lane = tid & 63;
  const int quad = lane >> 4;
  const int l16 = lane & 15;
  const int m0 = yb * 128;
  const int n0 = xb * 64;

  f32x4 acc[2][4];
  #pragma unroll
  for (int i = 0; i < 2; i++)
    #pragma unroll
    for (int jj = 0; jj < 4; jj++) acc[i][jj] = (f32x4){0.f, 0.f, 0.f, 0.f};

  const int ar = tid >> 2;
  const int ac = (tid & 3) * 8;

  f32x4 pf[4];
  u16x8 pb;
  {
    pf[0] = *(const f32x4*)(&A[(size_t)(m0 + ar) * GK + ac]);
    pf[1] = *(const f32x4*)(&A[(size_t)(m0 + ar) * GK + ac + 4]);
    pf[2] = *(const f32x4*)(&A[(size_t)(m0 + 64 + ar) * GK + ac]);
    pf[3] = *(const f32x4*)(&A[(size_t)(m0 + 64 + ar) * GK + ac + 4]);
    pb = *(const u16x8*)(&BT[(size_t)(n0 + ar) * GK + ac]);
  }

  for (int kt = 0; kt < 24; kt++) {
    u16x8 h0, h1;
    #pragma unroll
    for (int jj = 0; jj < 4; jj++) {
      h0[jj] = f2h(pf[0][jj]); h0[4 + jj] = f2h(pf[1][jj]);
      h1[jj] = f2h(pf[2][jj]); h1[4 + jj] = f2h(pf[3][jj]);
    }
    *(u16x8*)(&As[ar * 32 + ac]) = h0;
    *(u16x8*)(&As[(64 + ar) * 32 + ac]) = h1;
    *(u16x8*)(&Bs[ar * 32 + ac]) = pb;
    __syncthreads();

    if (kt + 1 < 24) {
      const int k0 = (kt + 1) * 32;
      pf[0] = *(const f32x4*)(&A[(size_t)(m0 + ar) * GK + k0 + ac]);
      pf[1] = *(const f32x4*)(&A[(size_t)(m0 + ar) * GK + k0 + ac + 4]);
      pf[2] = *(const f32x4*)(&A[(size_t)(m0 + 64 + ar) * GK + k0 + ac]);
      pf[3] = *(const f32x4*)(&A[(size_t)(m0 + 64 + ar) * GK + k0 + ac + 4]);
      pb = *(const u16x8*)(&BT[(size_t)(n0 + ar) * GK + k0 + ac]);
    }

    h16x8 af[2], bf[4];
    #pragma unroll
    for (int mf = 0; mf < 2; mf++)
      af[mf] = *(const h16x8*)(&As[(wave * 32 + mf * 16 + l16) * 32 + quad * 8]);
    #pragma unroll
    for (int nf = 0; nf < 4; nf++)
      bf[nf] = *(const h16x8*)(&Bs[(nf * 16 + l16) * 32 + quad * 8]);
    #pragma unroll
    for (int mf = 0; mf < 2; mf++)
      #pragma unroll
      for (int nf = 0; nf < 4; nf++)
        acc[mf][nf] = __builtin_amdgcn_mfma_f32_16x16x32_f16(af[mf], bf[nf], acc[mf][nf], 0, 0, 0);

    if (kt + 1 < 24) __syncthreads();
  }

  u16* Yr = (z == 0) ? Q16 : K16;
  #pragma unroll
  for (int nf = 0; nf < 4; nf++) {
    const int n = n0 + nf * 16 + l16;
    const float bv2 = bias[n];
    #pragma unroll
    for (int mf = 0; mf < 2; mf++) {
      const int m = m0 + wave * 32 + mf * 16 + quad * 4;
      if (z == 2) {
        const int b = m >> 11, s = m & 2047;
        u16x4 pk;
        #pragma unroll
        for (int r = 0; r < 4; r++) pk[r] = f2h(acc[mf][nf][r] + bv2);
        *(u16x4*)(&VT[(size_t)b * 768 * 2048 + (size_t)n * 2048 + s]) = pk;
      } else {
        #pragma unroll
        for (int r = 0; r < 4; r++)
          Yr[(size_t)(m + r) * GK + n] = f2h(acc[mf][nf][r] + bv2);
      }
    }
  }
}

// ---------------------------------------------------------------------------
// GEMM_O, 1-D grid 768, XCD-swizzled: y = c*8 + j/12, x = j%12.
// ---------------------------------------------------------------------------
__global__ __launch_bounds__(256) void gemm_o(
    const u16* __restrict__ A, const u16* __restrict__ BT,
    const float* __restrict__ bias, float* __restrict__ Y)
{
  const int bid = blockIdx.x;
  const int c = bid & 7, j = bid >> 3;
  const int yb = c * 8 + j / 12;
  const int xb = j % 12;

  __shared__ __align__(16) u16 As[128 * 32];
  __shared__ __align__(16) u16 Bs[64 * 32];
  const int tid = threadIdx.x;
  const int wave = tid >> 6;
  const int lane = tid & 63;
  const int quad = lane >> 4;
  const int l16 = lane & 15;
  const int m0 = yb * 128;
  const int n0 = xb * 64;

  f32x4 acc[2][4];
  #pragma unroll
  for (int i = 0; i < 2; i++)
    #pragma unroll
    for (int jj = 0; jj < 4; jj++) acc[i][jj] = (f32x4){0.f, 0.f, 0.f, 0.f};

  const int Lr = lane >> 2, Lc = (lane & 3) * 8;
  const u16* gA0 = A + (size_t)(m0 + wave * 32 + Lr) * GK + Lc;
  const u16* gA1 = gA0 + (size_t)16 * GK;
  const u16* gB  = BT + (size_t)(n0 + wave * 16 + Lr) * GK + Lc;
  u16* lA0 = &As[(wave * 32) * 32];
  u16* lA1 = &As[(wave * 32 + 16) * 32];
  u16* lB  = &Bs[(wave * 16) * 32];

  for (int kt = 0; kt < 24; kt++) {
    gll16(gA0, lA0);
    gll16(gA1, lA1);
    gll16(gB, lB);
    gA0 += 32; gA1 += 32; gB += 32;
    __syncthreads();

    h16x8 af[2], bf[4];
    #pragma unroll
    for (int mf = 0; mf < 2; mf++)
      af[mf] = *(const h16x8*)(&As[(wave * 32 + mf * 16 + l16) * 32 + quad * 8]);
    #pragma unroll
    for (int nf = 0; nf < 4; nf++)
      bf[nf] = *(const h16x8*)(&Bs[(nf * 16 + l16) * 32 + quad * 8]);
    #pragma unroll
    for (int mf = 0; mf < 2; mf++)
      #pragma unroll
      for (int nf = 0; nf < 4; nf++)
        acc[mf][nf] = __builtin_amdgcn_mfma_f32_16x16x32_f16(af[mf], bf[nf], acc[mf][nf], 0, 0, 0);
    __syncthreads();
  }

  #pragma unroll
  for (int nf = 0; nf < 4; nf++) {
    const int n = n0 + nf * 16 + l16;
    const float bv = bias[n];
    #pragma unroll
    for (int mf = 0; mf < 2; mf++) {
      const int m = m0 + wave * 32 + mf * 16 + quad * 4;
      #pragma unroll
      for (int r = 0; r < 4; r++)
        Y[(size_t)(m + r) * GK + n] = acc[mf][nf][r] + bv;
    }
  }
}

// ---------------------------------------------------------------------------
// Flash attention, S^T formulation, V^T input, 2 sets/wave x 8 waves.
// Block: 512 thr, 256 q-rows; wave owns 32 rows; lane owns 2 q-rows.
// LDS = 13312 + 13824 + 36864 = 64000 B (just under 64 KB cap). Grid (8,32).
// ---------------------------------------------------------------------------
#define SEQ 2048
#define LQK 104
#define LVT 72
#define LPS 72

__global__ __launch_bounds__(512, 2) void attn_kernel(
    const u16* __restrict__ Q, const u16* __restrict__ K,
    const u16* __restrict__ VT, u16* __restrict__ O)
{
  __shared__ __align__(16) u16 Ks[64 * LQK];     // 13312 B
  __shared__ __align__(16) u16 Vt[96 * LVT];     // 13824 B
  __shared__ __align__(16) u16 Ps[8][32 * LPS];  // 36864 B

  const int tid = threadIdx.x;
  const int wave = tid >> 6;        // 0..7
  const int lane = tid & 63;
  const int quad = lane >> 4;
  const int l16 = lane & 15;

  const int bh = blockIdx.y;
  const int b = bh >> 3, h = bh & 7;
  const int q0 = blockIdx.x * 256;

  const size_t batch_off = (size_t)b * SEQ * 768;
  const u16* Kg = K + batch_off + h * 96;
  const u16* Vg = VT + (size_t)b * 768 * 2048 + (size_t)(h * 96) * 2048;

  h16x8 qf[2][3];
  #pragma unroll
  for (int set = 0; set < 2; set++) {
    const u16* Qrow = Q + batch_off + (size_t)(q0 + wave * 32 + set * 16 + l16) * 768 + h * 96 + quad * 8;
    #pragma unroll
    for (int ks = 0; ks < 3; ks++) qf[set][ks] = *(const h16x8*)(&Qrow[ks * 32]);
  }

  const int kr0 = tid / 12, kc0 = (tid % 12) * 8;
  const int kr1 = (tid + 512) / 12, kc1 = ((tid + 512) % 12) * 8;
  const int vr0 = tid >> 3, vc0 = (tid & 7) * 8;
  const int vr1 = (tid + 512) >> 3, vc1 = ((tid + 512) & 7) * 8;
  const bool extra = tid < 256;

  f32x4 o[2][6];
  #pragma unroll
  for (int set = 0; set < 2; set++)
    #pragma unroll
    for (int i = 0; i < 6; i++) o[set][i] = (f32x4){0.f, 0.f, 0.f, 0.f};
  float m_raw[2] = {-1e30f, -1e30f}, lrow[2] = {0.f, 0.f};
  const float sc = 0.14724498f;  // log2(e)/sqrt(96)

  u16* Pw = &Ps[wave][0];

  u16x8 kA, kB, vA, vB;
  kA = *(const u16x8*)(&Kg[(size_t)kr0 * 768 + kc0]);
  vA = *(const u16x8*)(&Vg[(size_t)vr0 * 2048 + vc0]);
  if (extra) {
    kB = *(const u16x8*)(&Kg[(size_t)kr1 * 768 + kc1]);
    vB = *(const u16x8*)(&Vg[(size_t)vr1 * 2048 + vc1]);
  }

  for (int kt = 0; kt < SEQ / 64; kt++) {
    *(u16x8*)(&Ks[kr0 * LQK + kc0]) = kA;
    *(u16x8*)(&Vt[vr0 * LVT + vc0]) = vA;
    if (extra) {
      *(u16x8*)(&Ks[kr1 * LQK + kc1]) = kB;
      *(u16x8*)(&Vt[vr1 * LVT + vc1]) = vB;
    }
    __syncthreads();

    if (kt + 1 < SEQ / 64) {
      const u16* Kn = Kg + (size_t)(kt + 1) * 64 * 768;
      const u16* Vn = Vg + (size_t)(kt + 1) * 64;
      kA = *(const u16x8*)(&Kn[(size_t)kr0 * 768 + kc0]);
      vA = *(const u16x8*)(&Vn[(size_t)vr0 * 2048 + vc0]);
      if (extra) {
        kB = *(const u16x8*)(&Kn[(size_t)kr1 * 768 + kc1]);
        vB = *(const u16x8*)(&Vn[(size_t)vr1 * 2048 + vc1]);
      }
    }

    // S^T = K·Q^T, both sets share each Ks read
    f32x4 s[2][4];
    #pragma unroll
    for (int set = 0; set < 2; set++)
      #pragma unroll
      for (int kf = 0; kf < 4; kf++) s[set][kf] = (f32x4){0.f, 0.f, 0.f, 0.f};
    #pragma unroll
    for (int ks = 0; ks < 3; ks++) {
      #pragma unroll
      for (int kf = 0; kf < 4; kf++) {
        h16x8 a = *(const h16x8*)(&Ks[(kf * 16 + l16) * LQK + ks * 32 + quad * 8]);
        s[0][kf] = __builtin_amdgcn_mfma_f32_16x16x32_f16(a, qf[0][ks], s[0][kf], 0, 0, 0);
        s[1][kf] = __builtin_amdgcn_mfma_f32_16x16x32_f16(a, qf[1][ks], s[1][kf], 0, 0, 0);
      }
    }

    // online softmax per set
    #pragma unroll
    for (int set = 0; set < 2; set++) {
      float mx = s[set][0][0];
      #pragma unroll
      for (int kf = 0; kf < 4; kf++)
        #pragma unroll
        for (int r = 0; r < 4; r++) mx = fmaxf(mx, s[set][kf][r]);
      mx = fmaxf(mx, __shfl_xor(mx, 16));
      mx = fmaxf(mx, __shfl_xor(mx, 32));
      const float mold = m_raw[set];
      m_raw[set] = fmaxf(mold, mx);
      const float c0 = sc * m_raw[set];
      float ps = 0.f;
      #pragma unroll
      for (int kf = 0; kf < 4; kf++)
        #pragma unroll
        for (int r = 0; r < 4; r++) {
          float p = exp2f(fmaf(s[set][kf][r], sc, -c0));
          s[set][kf][r] = p;
          ps += p;
        }
      if (__any(m_raw[set] > mold)) {
        const float alpha = exp2f(sc * (mold - m_raw[set]));
        lrow[set] *= alpha;
        #pragma unroll
        for (int nfo = 0; nfo < 6; nfo++)
          #pragma unroll
          for (int r = 0; r < 4; r++) o[set][nfo][r] *= alpha;
      }
      lrow[set] += ps;

      #pragma unroll
      for (int kf = 0; kf < 4; kf++)
        #pragma unroll
        for (int rp = 0; rp < 4; rp += 2) {
          fp16x2 pk = __builtin_amdgcn_cvt_pkrtz(s[set][kf][rp], s[set][kf][rp + 1]);
          *(fp16x2*)(&Pw[(set * 16 + l16) * LPS + kf * 16 + quad * 4 + rp]) = pk;
        }
    }

    // O^T = V^T·P^T, both sets share each Vt read
    #pragma unroll
    for (int ks = 0; ks < 2; ks++) {
      h16x8 p0 = *(const h16x8*)(&Pw[l16 * LPS + ks * 32 + quad * 8]);
      h16x8 p1 = *(const h16x8*)(&Pw[(16 + l16) * LPS + ks * 32 + quad * 8]);
      #pragma unroll
      for (int nfo = 0; nfo < 6; nfo++) {
        h16x8 vfr = *(const h16x8*)(&Vt[(nfo * 16 + l16) * LVT + ks * 32 + quad * 8]);
        o[0][nfo] = __builtin_amdgcn_mfma_f32_16x16x32_f16(vfr, p0, o[0][nfo], 0, 0, 0);
        o[1][nfo] = __builtin_amdgcn_mfma_f32_16x16x32_f16(vfr, p1, o[1][nfo], 0, 0, 0);
      }
    }
    __syncthreads();
  }

  #pragma unroll
  for (int set = 0; set < 2; set++) {
    float l = lrow[set];
    l += __shfl_xor(l, 16);
    l += __shfl_xor(l, 32);
    const float inv = 1.0f / l;
    u16* Ob = O + batch_off + (size_t)(q0 + wave * 32 + set * 16 + l16) * 768 + h * 96;
    #pragma unroll
    for (int nfo = 0; nfo < 6; nfo++) {
      fp16x2 lo = __builtin_amdgcn_cvt_pkrtz(o[set][nfo][0] * inv, o[set][nfo][1] * inv);
      fp16x2 hi = __builtin_amdgcn_cvt_pkrtz(o[set][nfo][2] * inv, o[set][nfo][3] * inv);
      *(fp16x2*)(&Ob[nfo * 16 + quad * 4]) = lo;
      *(fp16x2*)(&Ob[nfo * 16 + quad * 4 + 2]) = hi;
    }
  }
}

// ---------------------------------------------------------------------------
extern "C" void kernel_launch(void* const* d_in, const int* in_sizes, int n_in,
                              void* d_out, int out_size, void* d_ws, size_t ws_size,
                              hipStream_t stream) {
  const float* Xq = (const float*)d_in[0];
  const float* Xk = (const float*)d_in[1];
  const float* Xv = (const float*)d_in[2];
  const float* Wq = (const float*)d_in[3];
  const float* bq = (const float*)d_in[4];
  const float* Wk = (const float*)d_in[5];
  const float* bk = (const float*)d_in[6];
  const float* Wv = (const float*)d_in[7];
  const float* bv = (const float*)d_in[8];
  const float* Wo = (const float*)d_in[9];
  const float* bo = (const float*)d_in[10];

  u16* wsu = (u16*)d_ws;
  u16* WT  = wsu;                    // WqT | WkT | WvT
  u16* WoT = wsu + 3 * 589824;
  u16* Q16 = wsu + 4 * 589824;       // 12.6 MB

  u16* outu = (u16*)d_out;
  u16* VTb = outu;                   // V^T f16 [4][768][2048]
  u16* K16 = outu + 6291456;         // K f16 rowmajor

  u16* A16 = (u16*)d_in[0];          // attn out (Xq dead after QKV GEMM)

  prep_kernel<<<1152, 256, 0, stream>>>(Wq, Wk, Wv, Wo, WT, WT + 589824, WT + 2 * 589824, WoT);
  gemm_qkv<<<2304, 256, 0, stream>>>(Xq, Xk, Xv, WT, bq, bk, bv, Q16, K16, VTb);
  attn_kernel<<<dim3(8, 32), 512, 0, stream>>>(Q16, K16, VTb, A16);
  gemm_o<<<768, 256, 0, stream>>>(A16, WoT, bo, (float*)d_out);
}